// Round 1
// 283.261 us; speedup vs baseline: 1.0131x; 1.0131x over previous
//
#include <hip/hip_runtime.h>
#include <hip/hip_fp16.h>

// Problem constants (match reference)
#define NC 128
#define NS 2048
#define NX 256
#define NZ 512
#define NROWS (NX * NZ)      // 131072 output pixels
#define NCOLS (NS * NC)      // 262144 rhs rows
#define RUN 16               // contiguous nnz per lane
#define WAVE_NNZ (RUN * 64)  // 1024 nnz per wave
#define NSLOTS 64            // LDS row-accumulator slots per wave

// NOTE: harness passes ALL integer inputs as int32.
// NOTE (r3): nontemporal loads on partial-line streams REGRESSED (+200MB).
// NOTE (r4): too-few waves (16/CU) -> occupancy-starved. Keep >=16K waves.
// NOTE (r5): per-lane GLOBAL atomics are HBM-side RMW on 8-XCD (L2s not
//            coherent): 10M atomics -> WRITE_SIZE 146MB, dep-chains of ~900cy.
//            Sink must be LDS-local; global atomics only at wave boundaries.
// NOTE (r6): VGPR_Count=52 with VALUBusy 3.9% + HBM 13% = latency-bound from
//            register-starved MLP. launch_bounds(256) alone let the backend
//            shrink regs below the ~95 needed to keep 12 stream loads + 16
//            gathers in flight. Fix: (256,4) cap=128 VGPR + sched_barrier(0)
//            pinning gather issuance before the accumulate loop.
// NOTE (r6): pack_rhs old mapping read x at 8KB lane stride (64 lines per
//            load instr, 32x amplification). New mapping: coalesced reads,
//            scattered 8B writes (stores don't stall; L2 merges lines).

struct alignas(8) Half4 { __half2 lo, hi; };

// Kernel 1: pack x (B,K,NC,NS) into fp16 rhs[j], j = s*NC + c.
// Thread mapping chosen so READS are coalesced (consecutive lanes =
// consecutive s). Writes are 8B at 1KB stride -> scattered, but stores are
// fire-and-forget and adjacent waves fill adjacent c of the same lines.
__global__ void pack_rhs_kernel(const float* __restrict__ x,
                                Half4* __restrict__ rhs) {
    int j = blockIdx.x * blockDim.x + threadIdx.x;
    if (j >= NCOLS) return;
    int c = j >> 11;         // 0..127
    int s = j & (NS - 1);    // 0..2047, consecutive within wave
    int base = c * NS + s;   // coalesced across lanes
    Half4 h;
    h.lo = __float22half2_rn(make_float2(x[base],               x[base + 1 * NC * NS]));
    h.hi = __float22half2_rn(make_float2(x[base + 2 * NC * NS], x[base + 3 * NC * NS]));
    rhs[s * NC + c] = h;
}

__device__ __forceinline__ void global_flush(float* __restrict__ out, int r, float4 a) {
    int ix = r >> 9;          // r / NZ
    int iz = r & (NZ - 1);    // r % NZ
    int o = iz * NX + ix;     // out[b, iz, ix]
    atomicAdd(&out[0 * NROWS + o], a.x);
    atomicAdd(&out[1 * NROWS + o], a.y);
    atomicAdd(&out[2 * NROWS + o], a.z);
    atomicAdd(&out[3 * NROWS + o], a.w);
}

// Kernel 2: wave owns 1024 contiguous nnz (lane: 16). Streams rows/cols/vals
// with aligned 16B loads, 16 independent fp16 gathers, lane-local segmented
// accumulate flushed to per-wave LDS slots (ds_add_f32). Epilogue: interior
// rows (fully owned, rows sorted) -> direct store; the 2 boundary rows ->
// global atomicAdd over memset-0 output.
// launch_bounds(256, 4): min 4 waves/EU = 16 waves/CU, VGPR cap 128 — enough
// to keep ALL 28 loads (12 stream + 16 gather) in flight per wave.
__global__ void __launch_bounds__(256, 4) spmm_seg_kernel(
        const float* __restrict__ vals,
        const int* __restrict__ cols,
        const int* __restrict__ rows,
        const Half4* __restrict__ rhs,
        float* __restrict__ out,
        int nnz) {
    __shared__ float sl[4][NSLOTS][4];   // 4KB per block

    int wv   = threadIdx.x >> 6;
    int lane = threadIdx.x & 63;
    int wid  = (blockIdx.x << 2) + wv;
    int base = wid * WAVE_NNZ + lane * RUN;

    // zero this block's LDS (256 threads x 1 float4 = 4KB)
    ((float4*)sl)[threadIdx.x] = make_float4(0.f, 0.f, 0.f, 0.f);
    __syncthreads();

    // ---- stream loads: 16 nnz per lane ----
    // Issue order: cols FIRST (gather addresses depend on them -> oldest in
    // vmcnt order), then vals/rows (independent, overlap the col wait).
    float4 v[4];
    int4   c4[4], r4[4];
    if (base + RUN <= nnz) {
        #pragma unroll
        for (int q = 0; q < 4; ++q) c4[q] = *(const int4*)(cols + base + 4 * q);
        #pragma unroll
        for (int q = 0; q < 4; ++q) v[q]  = *(const float4*)(vals + base + 4 * q);
        #pragma unroll
        for (int q = 0; q < 4; ++q) r4[q] = *(const int4*)(rows + base + 4 * q);
    } else {
        #pragma unroll
        for (int q = 0; q < 4; ++q) {
            #pragma unroll
            for (int k = 0; k < 4; ++k) {
                int e = base + 4 * q + k;
                int ec = e < nnz ? e : (nnz - 1);
                (&v[q].x)[k]  = e < nnz ? vals[ec] : 0.f;   // v=0: contributes nothing
                (&c4[q].x)[k] = cols[ec];
                (&r4[q].x)[k] = rows[ec];
            }
        }
    }

    // ---- 16 independent 8B gathers (L2-resident 2MB table) ----
    Half4 g[RUN];
    #pragma unroll
    for (int q = 0; q < 4; ++q) {
        g[4 * q + 0] = rhs[c4[q].x];
        g[4 * q + 1] = rhs[c4[q].y];
        g[4 * q + 2] = rhs[c4[q].z];
        g[4 * q + 3] = rhs[c4[q].w];
    }
    // Pin: ALL loads above must be issued before any consumption below.
    // Without this the backend sinks gathers into the accumulate loop to
    // save registers, serializing 16 L2-latency waits (the r5 kernel's
    // VGPR_Count=52 / VALUBusy=3.9% signature).
    __builtin_amdgcn_sched_barrier(0);

    int rfirst = __shfl(r4[0].x, 0);     // wave's first row
    int rlast  = __shfl(r4[3].w, 63);    // wave's last row

    // ---- lane-local segmented accumulate, flush to LDS slots ----
    int cur = r4[0].x;
    float4 acc = make_float4(0.f, 0.f, 0.f, 0.f);
    #pragma unroll
    for (int j = 0; j < RUN; ++j) {
        int   rj = (&r4[j >> 2].x)[j & 3];
        float vj = (&v[j >> 2].x)[j & 3];
        float2 lo = __half22float2(g[j].lo);
        float2 hi = __half22float2(g[j].hi);
        if (rj != cur) {                 // ~1.1 times per 16-run
            int s = cur - rfirst;
            if (s < NSLOTS) {
                atomicAdd(&sl[wv][s][0], acc.x);
                atomicAdd(&sl[wv][s][1], acc.y);
                atomicAdd(&sl[wv][s][2], acc.z);
                atomicAdd(&sl[wv][s][3], acc.w);
            } else {
                global_flush(out, cur, acc);   // span overflow: ~never
            }
            acc = make_float4(0.f, 0.f, 0.f, 0.f);
            cur = rj;
        }
        acc.x += vj * lo.x;
        acc.y += vj * lo.y;
        acc.z += vj * hi.x;
        acc.w += vj * hi.y;
    }
    {
        int s = cur - rfirst;
        if (s < NSLOTS) {
            atomicAdd(&sl[wv][s][0], acc.x);
            atomicAdd(&sl[wv][s][1], acc.y);
            atomicAdd(&sl[wv][s][2], acc.z);
            atomicAdd(&sl[wv][s][3], acc.w);
        } else {
            global_flush(out, cur, acc);
        }
    }

    __syncthreads();

    // ---- epilogue: one slot per lane ----
    int span = rlast - rfirst;
    if (lane <= span && lane < NSLOTS) {
        float ax = sl[wv][lane][0];
        float ay = sl[wv][lane][1];
        float az = sl[wv][lane][2];
        float aw = sl[wv][lane][3];
        int rr = rfirst + lane;
        int ix = rr >> 9;
        int iz = rr & (NZ - 1);
        int o = iz * NX + ix;
        if (lane == 0 || rr == rlast) {
            // boundary row: may be shared with neighbor wave
            atomicAdd(&out[0 * NROWS + o], ax);
            atomicAdd(&out[1 * NROWS + o], ay);
            atomicAdd(&out[2 * NROWS + o], az);
            atomicAdd(&out[3 * NROWS + o], aw);
        } else {
            // interior row: all its nnz are in this wave (rows sorted)
            out[0 * NROWS + o] = ax;
            out[1 * NROWS + o] = ay;
            out[2 * NROWS + o] = az;
            out[3 * NROWS + o] = aw;
        }
    }
}

// Fallback (workspace too small): inline bounds + direct fp32 gather from x.
__global__ void __launch_bounds__(256) spmm_direct_kernel(
        const float* __restrict__ x,
        const float* __restrict__ vals,
        const int* __restrict__ rows,
        const int* __restrict__ cols,
        int nnz,
        float* __restrict__ out) {
    int r = (blockIdx.x << 2) + (threadIdx.x >> 6);
    int lane = threadIdx.x & 63;
    int start, end;
    {
        int lo = 0, hi = nnz;
        while (lo < hi) { int mid = (lo + hi) >> 1; if (rows[mid] < r) lo = mid + 1; else hi = mid; }
        start = lo;
        hi = nnz;
        int key = r + 1;
        while (lo < hi) { int mid = (lo + hi) >> 1; if (rows[mid] < key) lo = mid + 1; else hi = mid; }
        end = lo;
    }
    float4 acc = {0.f, 0.f, 0.f, 0.f};
    for (int i = start + lane; i < end; i += 64) {
        float v = vals[i];
        int col = cols[i];
        int cc = col & (NC - 1);
        int ss = col >> 7;
        int b = cc * NS + ss;
        acc.x += v * x[b];
        acc.y += v * x[b + 1 * NC * NS];
        acc.z += v * x[b + 2 * NC * NS];
        acc.w += v * x[b + 3 * NC * NS];
    }
    #pragma unroll
    for (int off = 32; off >= 1; off >>= 1) {
        acc.x += __shfl_xor(acc.x, off, 64);
        acc.y += __shfl_xor(acc.y, off, 64);
        acc.z += __shfl_xor(acc.z, off, 64);
        acc.w += __shfl_xor(acc.w, off, 64);
    }
    if (lane < 4) {
        float o = (lane == 0) ? acc.x : (lane == 1) ? acc.y : (lane == 2) ? acc.z : acc.w;
        int ix = r >> 9;
        int iz = r & (NZ - 1);
        out[lane * NROWS + iz * NX + ix] = o;
    }
}

extern "C" void kernel_launch(void* const* d_in, const int* in_sizes, int n_in,
                              void* d_out, int out_size, void* d_ws, size_t ws_size,
                              hipStream_t stream) {
    const float* x        = (const float*)d_in[0];
    const float* csr_vals = (const float*)d_in[1];
    const int*   csr_rows = (const int*)d_in[2];   // int32 per harness contract
    const int*   csr_cols = (const int*)d_in[3];
    float* out = (float*)d_out;
    int nnz = in_sizes[1];

    size_t need = (size_t)NCOLS * sizeof(Half4);   // 2MB
    if (ws_size >= need) {
        Half4* rhs = (Half4*)d_ws;
        hipMemsetAsync(out, 0, (size_t)out_size * sizeof(float), stream);
        pack_rhs_kernel<<<(NCOLS + 255) / 256, 256, 0, stream>>>(x, rhs);
        int nblocks = (nnz + 4 * WAVE_NNZ - 1) / (4 * WAVE_NNZ);   // 4096 blocks, 16K waves
        spmm_seg_kernel<<<nblocks, 256, 0, stream>>>(csr_vals, csr_cols, csr_rows,
                                                     rhs, out, nnz);
    } else {
        spmm_direct_kernel<<<NROWS / 4, 256, 0, stream>>>(x, csr_vals, csr_rows, csr_cols, nnz, out);
    }
}